// Round 5
// baseline (123376.123 us; speedup 1.0000x reference)
//
#include <hip/hip_runtime.h>
#include <math.h>

// LSTM T=32768, B=1, I=128, H=512. Persistent kernel: 32 WGs x 576 threads.
// R5: wave0 = dedicated poller (tag-in-band 8B packets, relaxed agent atomics,
// per-lane early LDS broadcast into parity-double-buffered h_lds).
// Waves 1..8 each own 2 h elements end-to-end: 8 gate rows -> xor-reduce ->
// own activations -> publish own 2 packets. No 2nd syncthreads, no gate LDS,
// no per-step atomics: out[t-1] computed by WG0/wave1 from h_lds, plain store.

#define T_SEQ 32768
#define HID   512
#define INP   128
#define NWG   32
#define NTH   576   // 9 waves: wave0 poller + 8 compute waves
#define HSL   16    // h elements per WG
#define KW    64    // W_hh weights per thread
#define KX    16    // W_ih weights per thread

typedef unsigned long long u64;

__device__ __forceinline__ float fast_sigmoid(float x) {
    return 1.0f / (1.0f + __expf(-x));
}
__device__ __forceinline__ float fast_tanh(float x) {
    float a = fabsf(x);
    float e = __expf(-2.0f * a);          // underflows to 0 for large a -> r=1
    float r = (1.0f - e) / (1.0f + e);
    return copysignf(r, x);
}

__global__ void __launch_bounds__(NTH, 1) lstm_persist(
    const float* __restrict__ x,
    const float* __restrict__ W_ih,
    const float* __restrict__ W_hh,
    const float* __restrict__ b_ih,
    const float* __restrict__ b_hh,
    const float* __restrict__ W1,
    const float* __restrict__ b1,
    const float* __restrict__ Wout,
    u64* __restrict__ hbuf,             // 2 x 512 packets, pre-zeroed
    float* __restrict__ out)
{
    const int w   = blockIdx.x;
    const int tid = threadIdx.x;
    const int wv  = (tid >> 6) - 1;     // -1 = poller wave
    const int l   = tid & 63;
    const int rw  = l >> 3;             // 0..7: (gate g, elem b)
    const int j   = l & 7;              // K-chunk
    const int g   = rw >> 1;
    const int b   = rw & 1;

    const bool is_poll = (wv < 0);
    const bool is_comp = (wv >= 0);
    const bool is_out  = (w == 0 && wv == 0);   // WG0 wave1 computes out[]

    __shared__ float h_lds[2][HID];     // parity double buffer

    // ---- compute-wave weights (j-rotated order to match LDS read schedule) --
    int grow = 0;
    float wr[KW], wi[KX];
    float brow = 0.0f;
#pragma unroll
    for (int k = 0; k < KW; ++k) wr[k] = 0.0f;
#pragma unroll
    for (int k = 0; k < KX; ++k) wi[k] = 0.0f;
    if (is_comp) {
        grow = g * HID + w * HSL + 2 * wv + b;
#pragma unroll
        for (int kk = 0; kk < 16; ++kk) {
            const int p = (kk + 2 * j) & 15;
            const float4 v4 = *(const float4*)&W_hh[grow * HID + j * KW + 4 * p];
            wr[4 * kk + 0] = v4.x; wr[4 * kk + 1] = v4.y;
            wr[4 * kk + 2] = v4.z; wr[4 * kk + 3] = v4.w;
        }
#pragma unroll
        for (int k = 0; k < KX; k += 4) {
            const float4 v4 = *(const float4*)&W_ih[grow * INP + j * KX + k];
            wi[k] = v4.x; wi[k + 1] = v4.y; wi[k + 2] = v4.z; wi[k + 3] = v4.w;
        }
        brow = b_ih[grow] + b_hh[grow];
    }
    // out-projection weights for WG0/wave1: lane l covers h indices l+64*i
    float weff_o[8];
    float be = 0.0f;
#pragma unroll
    for (int i = 0; i < 8; ++i) weff_o[i] = 0.0f;
    if (is_out) {
#pragma unroll
        for (int i = 0; i < 8; ++i) {
            float s = 0.0f;
            for (int p = 0; p < 25; ++p) s += Wout[p] * W1[p * HID + l + 64 * i];
            weff_o[i] = s;
        }
        for (int p = 0; p < 25; ++p) be += b1[p] * Wout[p];
    }
    // pin against in-loop memory clobbers
#pragma unroll
    for (int k = 0; k < KW; ++k) asm volatile("" : "+v"(wr[k]));
#pragma unroll
    for (int k = 0; k < KX; ++k) asm volatile("" : "+v"(wi[k]));
#pragma unroll
    for (int i = 0; i < 8; ++i) asm volatile("" : "+v"(weff_o[i]));
    asm volatile("" : "+v"(brow));
    asm volatile("" : "+v"(be));

    if (is_poll) __builtin_amdgcn_s_setprio(3);

    float c = 0.0f;
    float xa[KX];
#pragma unroll
    for (int k = 0; k < KX; ++k) xa[k] = 0.0f;
    if (is_comp) {
#pragma unroll
        for (int k = 0; k < KX; ++k) xa[k] = x[j * KX + k];
    }

    for (unsigned int t = 0; t <= T_SEQ; ++t) {
        // ---- poller: wait for all 512 packets tagged t; early LDS write ----
        if (is_poll) {
            const u64* P = hbuf + (t & 1) * HID;
            bool mine = false;
            while (true) {
                if (!mine) {
                    u64 pr[8];
                    bool ok = true;
#pragma unroll
                    for (int i = 0; i < 8; ++i) {
                        pr[i] = __hip_atomic_load(&P[l + 64 * i],
                                                  __ATOMIC_RELAXED,
                                                  __HIP_MEMORY_SCOPE_AGENT);
                        ok = ok && ((unsigned int)(pr[i] >> 32) == t);
                    }
                    if (ok) {
#pragma unroll
                        for (int i = 0; i < 8; ++i)
                            h_lds[t & 1][l + 64 * i] =
                                __uint_as_float((unsigned int)pr[i]);
                        mine = true;
                    }
                }
                if (__ballot(mine) == ~0ull) break;
            }
        }
        __syncthreads();

        float hv = 0.0f;
        if (is_comp && t < T_SEQ) {
            float a0 = 0.0f, a1 = 0.0f, a2 = 0.0f, a3 = 0.0f;
#pragma unroll
            for (int k = 0; k < KX; k += 4) {
                a0 += wi[k + 0] * xa[k + 0];
                a1 += wi[k + 1] * xa[k + 1];
                a2 += wi[k + 2] * xa[k + 2];
                a3 += wi[k + 3] * xa[k + 3];
            }
            const float4* hl4 = (const float4*)&h_lds[t & 1][j * KW];
#pragma unroll
            for (int kk = 0; kk < 16; ++kk) {
                const int p = (kk + 2 * j) & 15;
                const float4 h4 = hl4[p];
                a0 += wr[4 * kk + 0] * h4.x;
                a1 += wr[4 * kk + 1] * h4.y;
                a2 += wr[4 * kk + 2] * h4.z;
                a3 += wr[4 * kk + 3] * h4.w;
            }
            // prefetch x_{t+1} (off critical path)
            const int tn = (t + 1 < T_SEQ) ? (int)(t + 1) : (T_SEQ - 1);
#pragma unroll
            for (int k = 0; k < KX; k += 4) {
                const float4 x4 = *(const float4*)&x[tn * INP + j * KX + k];
                xa[k + 0] = x4.x; xa[k + 1] = x4.y;
                xa[k + 2] = x4.z; xa[k + 3] = x4.w;
            }
            // xor-butterfly over the 8 j-lanes: every lane gets its row sum
            float acc = (a0 + a1) + (a2 + a3);
            acc += __shfl_xor(acc, 1);
            acc += __shfl_xor(acc, 2);
            acc += __shfl_xor(acc, 4);
            acc += brow;
            // gather the 4 gates of this wave's element b (lanes 0 and 8 valid)
            const float ig = acc;                    // rw = b     (gate i)
            const float fg = __shfl(acc, l + 16);    // rw = b + 2 (gate f)
            const float gg = __shfl(acc, l + 32);    // rw = b + 4 (gate g)
            const float og = __shfl(acc, l + 48);    // rw = b + 6 (gate o)
            const float iv = fast_sigmoid(ig);
            const float fv = fast_sigmoid(fg);
            const float gv = fast_tanh(gg);
            const float ov = fast_sigmoid(og);
            c = fv * c + iv * gv;
            hv = ov * fast_tanh(c);
        }

        // out[t-1] partial read (h_{t-1} = h_lds[t&1]) BEFORE publish
        float pd = 0.0f;
        if (is_out && t >= 1) {
#pragma unroll
            for (int i = 0; i < 8; ++i)
                pd += h_lds[t & 1][l + 64 * i] * weff_o[i];
        }
        asm volatile("" ::: "memory");   // keep LDS reads above the publish

        // publish this wave's 2 packets (lanes 0 and 8 hold valid hv)
        if (is_comp && t < T_SEQ && (j == 0) && (g == 0)) {   // l==0 || l==8
            const int e = w * HSL + 2 * wv + b;
            const u64 pkt = ((u64)(t + 1) << 32) | (u64)__float_as_uint(hv);
            __hip_atomic_store(&hbuf[((t + 1) & 1) * HID + e], pkt,
                               __ATOMIC_RELAXED, __HIP_MEMORY_SCOPE_AGENT);
        }

        if (is_out && t >= 1) {
            pd += __shfl_xor(pd, 1);
            pd += __shfl_xor(pd, 2);
            pd += __shfl_xor(pd, 4);
            pd += __shfl_xor(pd, 8);
            pd += __shfl_xor(pd, 16);
            pd += __shfl_xor(pd, 32);
            if (l == 0) out[t - 1] = pd + be;
        }
    }
}

extern "C" void kernel_launch(void* const* d_in, const int* in_sizes, int n_in,
                              void* d_out, int out_size, void* d_ws, size_t ws_size,
                              hipStream_t stream)
{
    const float* x    = (const float*)d_in[0];
    const float* W_ih = (const float*)d_in[1];
    const float* W_hh = (const float*)d_in[2];
    const float* b_ih = (const float*)d_in[3];
    const float* b_hh = (const float*)d_in[4];
    const float* W1   = (const float*)d_in[5];
    const float* b1   = (const float*)d_in[6];
    const float* Wout = (const float*)d_in[7];
    float* out = (float*)d_out;

    u64* hbuf = (u64*)d_ws;    // 2 x 512 packets = 8 KB

    // zero packets: tag 0 + h 0 == valid initial state for step 0
    hipMemsetAsync(d_ws, 0, 2 * HID * sizeof(u64), stream);
    lstm_persist<<<NWG, NTH, 0, stream>>>(x, W_ih, W_hh, b_ih, b_hh, W1, b1,
                                          Wout, hbuf, out);
}

// Round 6
// 65787.689 us; speedup vs baseline: 1.8754x; 1.8754x over previous
//
#include <hip/hip_runtime.h>
#include <math.h>

// LSTM T=32768, B=1, I=128, H=512. Persistent kernel: 32 WGs x 512 threads.
// R6: R4 skeleton (wave0 polls then computes — polling self-throttles during
// compute) + R5 row mapping (each wave owns 2 h elements end-to-end, no 2nd
// barrier, distributed activations, atomic-free out[]) + packed exchange:
// 2 h per 8B packet, 4-bit step tag in the even element's low mantissa bits
// (rel err 2^-19). 256 packets/parity; publish = one 8B store per wave.

#define T_SEQ 32768
#define HID   512
#define INP   128
#define NWG   32
#define NTH   512   // 8 waves; wave0 polls then computes
#define HSL   16    // h elements per WG
#define KW    64    // W_hh weights per thread
#define KX    16    // W_ih weights per thread
#define NPK   256   // packets per parity (2 h each)

typedef unsigned long long u64;
typedef unsigned int u32;

__device__ __forceinline__ float fast_sigmoid(float x) {
    return 1.0f / (1.0f + __expf(-x));
}
__device__ __forceinline__ float fast_tanh(float x) {
    float a = fabsf(x);
    float e = __expf(-2.0f * a);          // underflows to 0 for large a -> r=1
    float r = (1.0f - e) / (1.0f + e);
    return copysignf(r, x);
}

__global__ void __launch_bounds__(NTH, 2) lstm_persist(
    const float* __restrict__ x,
    const float* __restrict__ W_ih,
    const float* __restrict__ W_hh,
    const float* __restrict__ b_ih,
    const float* __restrict__ b_hh,
    const float* __restrict__ W1,
    const float* __restrict__ b1,
    const float* __restrict__ Wout,
    u64* __restrict__ hbuf,             // 2 x 256 packets, pre-zeroed
    float* __restrict__ out)
{
    const int w   = blockIdx.x;
    const int tid = threadIdx.x;
    const int wv  = tid >> 6;           // 0..7
    const int l   = tid & 63;
    const int rw  = l >> 3;             // 0..7 = (gate g, elem b)
    const int j   = l & 7;              // K-chunk
    const int g   = rw >> 1;
    const int b   = rw & 1;
    const bool is_out = (w == 0 && wv == 1);   // WG0 wave1 computes out[]

    __shared__ float h_lds[2][HID];     // parity double buffer

    // each wave owns elements {16w + 2wv, 16w + 2wv + 1}; 8 rows (4 gates x 2)
    const int grow = g * HID + w * HSL + 2 * wv + b;

    // ---- weights, j-rotated order to match the LDS read schedule ----
    float wr[KW], wi[KX];
#pragma unroll
    for (int kk = 0; kk < 16; ++kk) {
        const int p = (kk + 2 * j) & 15;
        const float4 v4 = *(const float4*)&W_hh[grow * HID + j * KW + 4 * p];
        wr[4 * kk + 0] = v4.x; wr[4 * kk + 1] = v4.y;
        wr[4 * kk + 2] = v4.z; wr[4 * kk + 3] = v4.w;
    }
#pragma unroll
    for (int k = 0; k < KX; k += 4) {
        const float4 v4 = *(const float4*)&W_ih[grow * INP + j * KX + k];
        wi[k] = v4.x; wi[k + 1] = v4.y; wi[k + 2] = v4.z; wi[k + 3] = v4.w;
    }
    float brow = b_ih[grow] + b_hh[grow];

    // out-projection weights (WG0 wave1): lane l covers h indices l + 64*i
    float weff_o[8];
    float be = 0.0f;
#pragma unroll
    for (int i = 0; i < 8; ++i) weff_o[i] = 0.0f;
    if (is_out) {
#pragma unroll
        for (int i = 0; i < 8; ++i) {
            float s = 0.0f;
            for (int p = 0; p < 25; ++p) s += Wout[p] * W1[p * HID + l + 64 * i];
            weff_o[i] = s;
        }
        for (int p = 0; p < 25; ++p) be += b1[p] * Wout[p];
    }
    // pin against in-loop memory clobbers
#pragma unroll
    for (int k = 0; k < KW; ++k) asm volatile("" : "+v"(wr[k]));
#pragma unroll
    for (int k = 0; k < KX; ++k) asm volatile("" : "+v"(wi[k]));
#pragma unroll
    for (int i = 0; i < 8; ++i) asm volatile("" : "+v"(weff_o[i]));
    asm volatile("" : "+v"(brow));
    asm volatile("" : "+v"(be));

    float c = 0.0f;
    float xa[KX];
#pragma unroll
    for (int k = 0; k < KX; ++k) xa[k] = x[j * KX + k];

    for (u32 t = 0; t <= T_SEQ; ++t) {
        if (t == T_SEQ && w != 0) break;   // only WG0 runs the tail iteration

        // ---- wave0 polls 256 packets (4 loads/lane, per-lane early-out) ----
        if (wv == 0) {
            const u64* P = hbuf + (t & 1) * NPK;
            float2* HL = (float2*)h_lds[t & 1];
            bool mine = false;
            while (true) {
                if (!mine) {
                    u64 pr[4];
                    bool ok = true;
#pragma unroll
                    for (int i = 0; i < 4; ++i) {
                        pr[i] = __hip_atomic_load(&P[l + 64 * i],
                                                  __ATOMIC_RELAXED,
                                                  __HIP_MEMORY_SCOPE_AGENT);
                        ok = ok && ((((u32)pr[i]) ^ t) & 15u) == 0u;
                    }
                    if (ok) {
#pragma unroll
                        for (int i = 0; i < 4; ++i) {
                            float2 hp;
                            hp.x = __uint_as_float((u32)pr[i]);
                            hp.y = __uint_as_float((u32)(pr[i] >> 32));
                            HL[l + 64 * i] = hp;   // h[2p], h[2p+1]
                        }
                        mine = true;
                    }
                }
                if (__ballot(mine) == ~0ull) break;
            }
        }
        __syncthreads();

        float hv = 0.0f;
        if (t < T_SEQ) {
            float a0 = 0.0f, a1 = 0.0f, a2 = 0.0f, a3 = 0.0f;
#pragma unroll
            for (int k = 0; k < KX; k += 4) {
                a0 += wi[k + 0] * xa[k + 0];
                a1 += wi[k + 1] * xa[k + 1];
                a2 += wi[k + 2] * xa[k + 2];
                a3 += wi[k + 3] * xa[k + 3];
            }
            const float4* hl4 = (const float4*)&h_lds[t & 1][j * KW];
#pragma unroll
            for (int kk = 0; kk < 16; ++kk) {
                const int p = (kk + 2 * j) & 15;
                const float4 h4 = hl4[p];
                a0 += wr[4 * kk + 0] * h4.x;
                a1 += wr[4 * kk + 1] * h4.y;
                a2 += wr[4 * kk + 2] * h4.z;
                a3 += wr[4 * kk + 3] * h4.w;
            }
            // prefetch x_{t+1} (off critical path)
            const int tn = (t + 1 < T_SEQ) ? (int)(t + 1) : (T_SEQ - 1);
#pragma unroll
            for (int k = 0; k < KX; k += 4) {
                const float4 x4 = *(const float4*)&x[tn * INP + j * KX + k];
                xa[k + 0] = x4.x; xa[k + 1] = x4.y;
                xa[k + 2] = x4.z; xa[k + 3] = x4.w;
            }
            // xor-butterfly over j: every lane holds its row's full sum
            float acc = (a0 + a1) + (a2 + a3);
            acc += __shfl_xor(acc, 1);
            acc += __shfl_xor(acc, 2);
            acc += __shfl_xor(acc, 4);
            acc += brow;
            // gates of element b live at rw = b, b+2, b+4, b+6 (valid l<16)
            const float ig = acc;
            const float fg = __shfl(acc, l + 16);
            const float gg = __shfl(acc, l + 32);
            const float og = __shfl(acc, l + 48);
            const float iv = fast_sigmoid(ig);
            const float fv = fast_sigmoid(fg);
            const float gv = fast_tanh(gg);
            const float ov = fast_sigmoid(og);
            c = fv * c + iv * gv;
            hv = ov * fast_tanh(c);
            // pack (h_even tagged in low nibble, h_odd full) and publish:
            // one 8B store from lane 0 of each wave
            const float hv1 = __shfl(hv, 8);     // element b=1 (lane 8)
            if (l == 0) {
                const u32 b0 = (__float_as_uint(hv) & ~15u) | ((t + 1) & 15u);
                const u32 b1v = __float_as_uint(hv1);
                const u64 pkt = ((u64)b1v << 32) | (u64)b0;
                __hip_atomic_store(&hbuf[((t + 1) & 1) * NPK + w * 8 + wv], pkt,
                                   __ATOMIC_RELAXED, __HIP_MEMORY_SCOPE_AGENT);
            }
        }

        // out[t-1] = dot(h_{t-1}, w_eff) + b_eff — WG0 wave1, after publish
        if (is_out && t >= 1) {
            float pd = 0.0f;
#pragma unroll
            for (int i = 0; i < 8; ++i)
                pd += h_lds[t & 1][l + 64 * i] * weff_o[i];
            pd += __shfl_xor(pd, 1);
            pd += __shfl_xor(pd, 2);
            pd += __shfl_xor(pd, 4);
            pd += __shfl_xor(pd, 8);
            pd += __shfl_xor(pd, 16);
            pd += __shfl_xor(pd, 32);
            if (l == 0) out[t - 1] = pd + be;
        }
    }
}

extern "C" void kernel_launch(void* const* d_in, const int* in_sizes, int n_in,
                              void* d_out, int out_size, void* d_ws, size_t ws_size,
                              hipStream_t stream)
{
    const float* x    = (const float*)d_in[0];
    const float* W_ih = (const float*)d_in[1];
    const float* W_hh = (const float*)d_in[2];
    const float* b_ih = (const float*)d_in[3];
    const float* b_hh = (const float*)d_in[4];
    const float* W1   = (const float*)d_in[5];
    const float* b1   = (const float*)d_in[6];
    const float* Wout = (const float*)d_in[7];
    float* out = (float*)d_out;

    u64* hbuf = (u64*)d_ws;    // 2 x 256 packets = 4 KB

    // zero packets: tag nibble 0 + h 0 == valid initial state for step 0
    hipMemsetAsync(d_ws, 0, 2 * NPK * sizeof(u64), stream);
    lstm_persist<<<NWG, NTH, 0, stream>>>(x, W_ih, W_hh, b_ih, b_hh, W1, b1,
                                          Wout, hbuf, out);
}